// Round 17
// baseline (298.243 us; speedup 1.0000x reference)
//
#include <hip/hip_runtime.h>
#include <hip/hip_bf16.h>

#define DIN 49
#define HIN 32
#define WIN 64
#define CIN 32
#define DOUT 193
#define HOUT 256
#define WOUT 512
#define NPIX (HOUT * WOUT)      // 131072
#define NUPS (DOUT * NPIX)      // 25296896
#define NCONV (DIN * HIN * WIN) // 100352
#define NZ 2  // z0: d 0..95, z1: d 96..192. 1024 blocks -> 3 blocks/CU
              // (LDS 53.2KB x 3 = 159.7KB fits) = 12 waves/CU, +50% TLP.
#define ZSPAN 96
#define CGRP 8 // conv channel groups (4 ci each)

// LGA LDS geometry: bf16-packed, d-contiguous per pixel, dot2-consumed
// (R13). CHUNK=16 (R14): PIXW=10 words/pixel, double-buffered 2 x 25.8 KB.
#define ROWSTRIDE 33 // pixel-row stride in pixels
#define PIXW 10      // words per pixel
#define SUWORDS (20 * ROWSTRIDE * PIXW) // 6600 words per buffer
#define CHUNK 16
#define NPL 18   // CHUNK + 2 halo planes
// staging jobs: 20 rows x 4 segs x 18 planes = 1440; k<6 with tail 160
#define JGUARD(k, tid) ((k) < 5 || (tid) < 160)

typedef __attribute__((ext_vector_type(2))) float v2f;

// v_dot2_f32_bf16: d = a.lo*b.lo + a.hi*b.hi + c (packed bf16 operands).
__device__ __forceinline__ float dot2bf(unsigned a, unsigned b, float c) {
    float d;
    asm("v_dot2_f32_bf16 %0, %1, %2, %3"
        : "=v"(d)
        : "v"(a), "v"(b), "v"(c));
    return d;
}

// ---------------------------------------------------------------------------
// Kernel 1: 3x3x3 conv, 32 -> 1 ch, zero pad 1, split 8 ways over channels.
// 4-wide w-vectorized (R10 measured win).
// ---------------------------------------------------------------------------
__global__ void conv3d_kernel(const float* __restrict__ x,
                              const float* __restrict__ w,
                              float* __restrict__ partial) {
    __shared__ float ws[4 * 27];
    const int grp = blockIdx.y;
    for (int t = threadIdx.x; t < 4 * 27; t += blockDim.x)
        ws[t] = w[grp * (4 * 27) + t];
    __syncthreads();

    int idx4 = blockIdx.x * blockDim.x + threadIdx.x; // 25088 = 98*256 exact
    int w4 = idx4 & 15;  // WIN/4 = 16
    int t2 = idx4 >> 4;
    int hq = t2 & 31;    // HIN = 32
    int dq = t2 >> 5;    // dq in [0, 49)
    int wq0 = w4 * 4;

    float acc0 = 0.f, acc1 = 0.f, acc2 = 0.f, acc3 = 0.f;
    const float* xg = x + (size_t)grp * 4 * NCONV;
#pragma unroll
    for (int cl = 0; cl < 4; ++cl) {
        const float* xb = xg + cl * NCONV;
        const float* wb = ws + cl * 27;
#pragma unroll
        for (int kd = 0; kd < 3; ++kd) {
            int zd = dq + kd - 1;
            if (zd < 0 || zd >= DIN) continue;
#pragma unroll
            for (int kh = 0; kh < 3; ++kh) {
                int zh = hq + kh - 1;
                if (zh < 0 || zh >= HIN) continue;
                const float* row = xb + (zd * HIN + zh) * WIN;
                float4 v = *(const float4*)(row + wq0);
                float xl = (wq0 > 0) ? row[wq0 - 1] : 0.f;
                float xr = (wq0 < WIN - 4) ? row[wq0 + 4] : 0.f;
                float w0 = wb[(kd * 3 + kh) * 3 + 0];
                float w1 = wb[(kd * 3 + kh) * 3 + 1];
                float w2 = wb[(kd * 3 + kh) * 3 + 2];
                acc0 = fmaf(w0, xl, acc0);
                acc0 = fmaf(w1, v.x, acc0);
                acc0 = fmaf(w2, v.y, acc0);
                acc1 = fmaf(w0, v.x, acc1);
                acc1 = fmaf(w1, v.y, acc1);
                acc1 = fmaf(w2, v.z, acc1);
                acc2 = fmaf(w0, v.y, acc2);
                acc2 = fmaf(w1, v.z, acc2);
                acc2 = fmaf(w2, v.w, acc2);
                acc3 = fmaf(w0, v.z, acc3);
                acc3 = fmaf(w1, v.w, acc3);
                acc3 = fmaf(w2, xr, acc3);
            }
        }
    }
    float4 o4 = make_float4(acc0, acc1, acc2, acc3);
    *(float4*)(partial + (size_t)grp * NCONV + (size_t)idx4 * 4) = o4;
}

// ---------------------------------------------------------------------------
// Kernel 1b: fold 8 conv partials -> c. float4-vectorized.
// ---------------------------------------------------------------------------
__global__ void convfold_kernel(const float* __restrict__ partial,
                                float* __restrict__ c) {
    int i4 = blockIdx.x * blockDim.x + threadIdx.x; // NCONV/4 = 25088
    float4 s = *(const float4*)(partial + (size_t)i4 * 4);
#pragma unroll
    for (int g = 1; g < CGRP; ++g) {
        float4 v = *(const float4*)(partial + (size_t)g * NCONV +
                                    (size_t)i4 * 4);
        s.x += v.x;
        s.y += v.y;
        s.z += v.z;
        s.w += v.w;
    }
    *(float4*)(c + (size_t)i4 * 4) = s;
}

__device__ __forceinline__ unsigned short bf16bits(float f) {
    __hip_bfloat16 h = __float2bfloat16(f);
    unsigned short b;
    __builtin_memcpy(&b, &h, 2);
    return b;
}

// Tap body for CHUNK=16: 9 LDS words (4x b64 + b32), 32 dot2, one set of
// packed weight words per tap. gp[] holds bf16 channel pairs; parity of t
// selects halves at compile time.
#define TAP16(sp, t)                                                 \
    do {                                                             \
        unsigned u0, u1, u2, u3, u4, u5, u6, u7, u8;                 \
        { uint2 q = *(const uint2*)(sp);       u0 = q.x; u1 = q.y; } \
        { uint2 q = *(const uint2*)((sp) + 2); u2 = q.x; u3 = q.y; } \
        { uint2 q = *(const uint2*)((sp) + 4); u4 = q.x; u5 = q.y; } \
        { uint2 q = *(const uint2*)((sp) + 6); u6 = q.x; u7 = q.y; } \
        u8 = (sp)[8];                                                \
        const unsigned g0w = gp[(t) >> 1];                           \
        const unsigned g1w = gp[(25 + (t)) >> 1];                    \
        const unsigned g2w = gp[(50 + (t)) >> 1];                    \
        unsigned W10, W2z, Wz1, W02;                                 \
        if ((t) & 1) {                                               \
            W10 = (g1w & 0xFFFFu) | (g0w & 0xFFFF0000u);             \
            W2z = g2w >> 16;                                         \
            Wz1 = g1w << 16;                                         \
            W02 = (g0w >> 16) | (g2w & 0xFFFF0000u);                 \
        } else {                                                     \
            W10 = (g1w >> 16) | (g0w << 16);                         \
            W2z = g2w & 0xFFFFu;                                     \
            Wz1 = g1w & 0xFFFF0000u;                                 \
            W02 = (g0w & 0xFFFFu) | (g2w << 16);                     \
        }                                                            \
        acc[0] = dot2bf(u0, W10, acc[0]);                            \
        acc[0] = dot2bf(u1, W2z, acc[0]);                            \
        acc[1] = dot2bf(u0, Wz1, acc[1]);                            \
        acc[1] = dot2bf(u1, W02, acc[1]);                            \
        acc[2] = dot2bf(u1, W10, acc[2]);                            \
        acc[2] = dot2bf(u2, W2z, acc[2]);                            \
        acc[3] = dot2bf(u1, Wz1, acc[3]);                            \
        acc[3] = dot2bf(u2, W02, acc[3]);                            \
        acc[4] = dot2bf(u2, W10, acc[4]);                            \
        acc[4] = dot2bf(u3, W2z, acc[4]);                            \
        acc[5] = dot2bf(u2, Wz1, acc[5]);                            \
        acc[5] = dot2bf(u3, W02, acc[5]);                            \
        acc[6] = dot2bf(u3, W10, acc[6]);                            \
        acc[6] = dot2bf(u4, W2z, acc[6]);                            \
        acc[7] = dot2bf(u3, Wz1, acc[7]);                            \
        acc[7] = dot2bf(u4, W02, acc[7]);                            \
        acc[8] = dot2bf(u4, W10, acc[8]);                            \
        acc[8] = dot2bf(u5, W2z, acc[8]);                            \
        acc[9] = dot2bf(u4, Wz1, acc[9]);                            \
        acc[9] = dot2bf(u5, W02, acc[9]);                            \
        acc[10] = dot2bf(u5, W10, acc[10]);                          \
        acc[10] = dot2bf(u6, W2z, acc[10]);                          \
        acc[11] = dot2bf(u5, Wz1, acc[11]);                          \
        acc[11] = dot2bf(u6, W02, acc[11]);                          \
        acc[12] = dot2bf(u6, W10, acc[12]);                          \
        acc[12] = dot2bf(u7, W2z, acc[12]);                          \
        acc[13] = dot2bf(u6, Wz1, acc[13]);                          \
        acc[13] = dot2bf(u7, W02, acc[13]);                          \
        acc[14] = dot2bf(u7, W10, acc[14]);                          \
        acc[14] = dot2bf(u8, W2z, acc[14]);                          \
        acc[15] = dot2bf(u7, Wz1, acc[15]);                          \
        acc[15] = dot2bf(u8, W02, acc[15]);                          \
    } while (0)

// Tail tap (d = 192 only, z1): out = g1*u[191] + g0*u[192] (u[193] is
// zero-padded). One dot2 per tap on word 0.
#define TAPTAIL(sp, t)                                               \
    do {                                                             \
        unsigned u0 = (sp)[0];                                       \
        const unsigned g0w = gp[(t) >> 1];                           \
        const unsigned g1w = gp[(25 + (t)) >> 1];                    \
        unsigned W10;                                                \
        if ((t) & 1)                                                 \
            W10 = (g1w & 0xFFFFu) | (g0w & 0xFFFF0000u);             \
        else                                                         \
            W10 = (g1w >> 16) | (g0w << 16);                         \
        acc0 = dot2bf(u0, W10, acc0);                                \
    } while (0)

// job decode (1440 jobs): seg in [0,4), dl in [0,18), r in [0,20)
__device__ __forceinline__ void jdec(int j, int& seg, int& dl, int& r) {
    seg = j & 3;
    int rowjob = j >> 2; // [0, 360)
    dl = rowjob / 20;
    r = rowjob - dl * 20;
}

// ---------------------------------------------------------------------------
// lga1 staging phase A: trilinear d/h-lerp from c (L2-hot) into packed
// bf16 regs (9 regs for 6 jobs). Issued EARLY (T14).
// ---------------------------------------------------------------------------
__device__ __forceinline__ void stageA1(const float* __restrict__ cvol,
                                        int tid, int h0p, int w0p, int dstart,
                                        unsigned (&aq0)[6], unsigned (&aq2)[3]) {
    aq2[0] = 0u;
    aq2[1] = 0u;
    aq2[2] = 0u;
#pragma unroll
    for (int k = 0; k < 6; ++k) {
        const bool a = JGUARD(k, tid);
        int j = tid + k * 256;
        int seg, dl, r;
        jdec(j, seg, dl, r);
        int gh = h0p - 2 + r;
        int gwb = w0p - 8 + seg * 8;
        int gd = dstart - 1 + dl;
        if (a && gd >= 0 && gd < DOUT && gh >= 0 && gh < HOUT && gwb >= 0 &&
            (gwb + 8) <= WOUT) {
            float fd = (gd + 0.5f) * (49.0f / 193.0f) - 0.5f;
            fd = fminf(fmaxf(fd, 0.f), (float)(DIN - 1));
            int d0c = min((int)fd, DIN - 2);
            float ad = fd - (float)d0c;
            float fh = (gh + 0.5f) * 0.125f - 0.5f;
            fh = fminf(fmaxf(fh, 0.f), (float)(HIN - 1));
            int h0c = min((int)fh, HIN - 2);
            float ah = fh - (float)h0c;
            int g = gwb >> 3;
            int cm1 = max(g - 1, 0);
            int cp1 = min(g + 1, WIN - 1);
            const float* p00 = cvol + (d0c * HIN + h0c) * WIN;
            const float* p01 = p00 + WIN;
            const float* p10 = p00 + HIN * WIN;
            const float* p11 = p10 + WIN;
            float q00, q01, q10, q11, a0, a1, a2;
            q00 = p00[cm1]; q01 = p01[cm1];
            q10 = p10[cm1]; q11 = p11[cm1];
            a0 = (q00 + ah * (q01 - q00)) * (1.f - ad) +
                 (q10 + ah * (q11 - q10)) * ad;
            q00 = p00[g]; q01 = p01[g];
            q10 = p10[g]; q11 = p11[g];
            a1 = (q00 + ah * (q01 - q00)) * (1.f - ad) +
                 (q10 + ah * (q11 - q10)) * ad;
            q00 = p00[cp1]; q01 = p01[cp1];
            q10 = p10[cp1]; q11 = p11[cp1];
            a2 = (q00 + ah * (q01 - q00)) * (1.f - ad) +
                 (q10 + ah * (q11 - q10)) * ad;
            aq0[k] = (unsigned)bf16bits(a0) | ((unsigned)bf16bits(a1) << 16);
            aq2[k >> 1] |= ((unsigned)bf16bits(a2)) << ((k & 1) * 16);
        } else {
            aq0[k] = 0u;
        }
    }
}

// lga1 scatter phase B: w-lerp from regs, bf16 half-word stores into LDS.
__device__ __forceinline__ void scat1(unsigned short* __restrict__ su16,
                                      int tid, const unsigned (&aq0)[6],
                                      const unsigned (&aq2)[3]) {
#pragma unroll
    for (int k = 0; k < 6; ++k) {
        if (JGUARD(k, tid)) {
            int j = tid + k * 256;
            int seg, dl, r;
            jdec(j, seg, dl, r);
            int hb = (r * ROWSTRIDE + seg * 8) * (2 * PIXW) + dl;
            float a0 = __uint_as_float(aq0[k] << 16);
            float a1 = __uint_as_float(aq0[k] & 0xFFFF0000u);
            float a2 = __uint_as_float((k & 1) ? (aq2[k >> 1] & 0xFFFF0000u)
                                               : (aq2[k >> 1] << 16));
            float d01 = a1 - a0, d12 = a2 - a1;
            su16[hb + 0 * 2 * PIXW] = bf16bits(a0 + 0.5625f * d01);
            su16[hb + 1 * 2 * PIXW] = bf16bits(a0 + 0.6875f * d01);
            su16[hb + 2 * 2 * PIXW] = bf16bits(a0 + 0.8125f * d01);
            su16[hb + 3 * 2 * PIXW] = bf16bits(a0 + 0.9375f * d01);
            su16[hb + 4 * 2 * PIXW] = bf16bits(a1 + 0.0625f * d12);
            su16[hb + 5 * 2 * PIXW] = bf16bits(a1 + 0.1875f * d12);
            su16[hb + 6 * 2 * PIXW] = bf16bits(a1 + 0.3125f * d12);
            su16[hb + 7 * 2 * PIXW] = bf16bits(a1 + 0.4375f * d12);
        }
    }
}

// lga2 staging phase A: one uint4 (8 bf16) HBM load per job into regs.
__device__ __forceinline__ void stageA2(const unsigned short* __restrict__ xus,
                                        int tid, int h0p, int w0p, int dstart,
                                        uint4 (&dat)[6]) {
#pragma unroll
    for (int k = 0; k < 6; ++k) {
        const bool a = JGUARD(k, tid);
        int j = tid + k * 256;
        int seg, dl, r;
        jdec(j, seg, dl, r);
        int gh = h0p - 2 + r;
        int gwb = w0p - 8 + seg * 8;
        int gd = dstart - 1 + dl;
        uint4 v = make_uint4(0u, 0u, 0u, 0u);
        if (a && gd >= 0 && gd < DOUT && gh >= 0 && gh < HOUT && gwb >= 0 &&
            (gwb + 8) <= WOUT)
            v = *(const uint4*)(xus + (size_t)gd * NPIX + gh * WOUT + gwb);
        dat[k] = v;
    }
}

// lga2 scatter phase B: bf16 half-word stores straight from packed regs.
__device__ __forceinline__ void scat2(unsigned short* __restrict__ su16,
                                      int tid, const uint4 (&dat)[6]) {
#pragma unroll
    for (int k = 0; k < 6; ++k) {
        if (JGUARD(k, tid)) {
            int j = tid + k * 256;
            int seg, dl, r;
            jdec(j, seg, dl, r);
            int hb = (r * ROWSTRIDE + seg * 8) * (2 * PIXW) + dl;
            su16[hb + 0 * 2 * PIXW] = (unsigned short)(dat[k].x);
            su16[hb + 1 * 2 * PIXW] = (unsigned short)(dat[k].x >> 16);
            su16[hb + 2 * 2 * PIXW] = (unsigned short)(dat[k].y);
            su16[hb + 3 * 2 * PIXW] = (unsigned short)(dat[k].y >> 16);
            su16[hb + 4 * 2 * PIXW] = (unsigned short)(dat[k].z);
            su16[hb + 5 * 2 * PIXW] = (unsigned short)(dat[k].z >> 16);
            su16[hb + 6 * 2 * PIXW] = (unsigned short)(dat[k].w);
            su16[hb + 7 * 2 * PIXW] = (unsigned short)(dat[k].w >> 16);
        }
    }
}

// ---------------------------------------------------------------------------
// LGA pass 1. bf16 double-buffered su + dot2 taps; per z-block 6 full
// chunks (+1-plane d=192 epilogue on z1). setprio around taps (R15 win).
// amdgpu_num_vgpr(128) pin.
// ---------------------------------------------------------------------------
__global__ __launch_bounds__(256)
__attribute__((amdgpu_num_vgpr(128))) void lga1_kernel(
    const float* __restrict__ cvol,
    const float* __restrict__ lg1,
    __hip_bfloat16* __restrict__ yout) {
    const int tid = threadIdx.x;
    const int tx = tid & 15;
    const int ty = tid >> 4;
    const int w0p = blockIdx.x * 16;
    const int h0p = blockIdx.y * 16;
    const int zb = blockIdx.z * ZSPAN;
    const bool lastz = (blockIdx.z == NZ - 1);
    const int pix = (h0p + ty) * WOUT + (w0p + tx);

    __shared__ __align__(16) unsigned su[2 * SUWORDS];

    // prologue phase A (chunk 0): loads land under the guidance preamble
    unsigned aq0[6], aq2[3];
    stageA1(cvol, tid, h0p, w0p, zb, aq0, aq2);

    // ---- guidance: single pass, un-normalized, bf16 pairs (38 regs) ----
    float asum = 0.f;
    unsigned gp[38];
#pragma unroll
    for (int p = 0; p < 38; ++p) {
        int c0 = 2 * p, c1 = 2 * p + 1;
        float w0 = lg1[c0 * NPIX + pix];
        float w1 = (c1 < 75) ? lg1[c1 * NPIX + pix] : 0.f;
        unsigned b0 = bf16bits(w0), b1 = bf16bits(w1);
        asum += fabsf(__uint_as_float(b0 << 16)) +
                fabsf(__uint_as_float(b1 << 16));
        gp[p] = b0 | (b1 << 16);
    }
    const float inv = 1.f / fmaxf(asum, 1e-12f);

    const int pbase = (ty * ROWSTRIDE + tx + 6) * PIXW;
    __hip_bfloat16* ybase = yout + pix;

    scat1((unsigned short*)su, tid, aq0, aq2); // first chunk -> buf0
    int pb = 0;
    for (int d0 = zb; d0 < zb + ZSPAN; d0 += CHUNK) { // 6 full chunks
        __syncthreads(); // buf[pb] writes visible; buf[pb^1] readers done
        const bool hn = lastz ? (d0 + CHUNK < DOUT)
                              : (d0 + CHUNK < zb + ZSPAN);
        if (hn) stageA1(cvol, tid, h0p, w0p, d0 + CHUNK, aq0, aq2);

        const unsigned* sw = su + pb * SUWORDS + pbase;
        float acc[16];
#pragma unroll
        for (int d = 0; d < 16; ++d) acc[d] = 0.f;
        __builtin_amdgcn_s_setprio(1);
#pragma unroll
        for (int i = 0; i < 5; ++i) {
#pragma unroll
            for (int j = 0; j < 5; ++j) {
                const int t = i * 5 + j;
                TAP16(sw + (i * ROWSTRIDE + j) * PIXW, t);
            }
        }
        __builtin_amdgcn_s_setprio(0);

        if (hn) scat1((unsigned short*)(su + (pb ^ 1) * SUWORDS), tid, aq0,
                      aq2);

#pragma unroll
        for (int dd = 0; dd < CHUNK; ++dd)
            ybase[(size_t)(d0 + dd) * NPIX] = __float2bfloat16(acc[dd] * inv);
        pb ^= 1;
    }

    if (lastz) { // epilogue: d = 192 only — one dot2 per tap
        __syncthreads();
        const unsigned* sw = su + pb * SUWORDS + pbase;
        float acc0 = 0.f;
#pragma unroll
        for (int i = 0; i < 5; ++i) {
#pragma unroll
            for (int j = 0; j < 5; ++j) {
                const int t = i * 5 + j;
                TAPTAIL(sw + (i * ROWSTRIDE + j) * PIXW, t);
            }
        }
        ybase[(size_t)192 * NPIX] = __float2bfloat16(acc0 * inv);
    }
}

// ---------------------------------------------------------------------------
// LGA pass 2: same structure; softmin WITHOUT online max (|v| <= max|u| =
// O(10) since guidance is L1-normalized -> raw expf cannot overflow fp32;
// all-positive sums, no cancellation). Per-z (l, s) partials merge with
// plain adds in reduce2.
// ---------------------------------------------------------------------------
__global__ __launch_bounds__(256)
__attribute__((amdgpu_num_vgpr(128))) void lga2_kernel(
    const __hip_bfloat16* __restrict__ xin,
    const float* __restrict__ lg1,
    float* __restrict__ part) {
    const int tid = threadIdx.x;
    const int tx = tid & 15;
    const int ty = tid >> 4;
    const int w0p = blockIdx.x * 16;
    const int h0p = blockIdx.y * 16;
    const int zb = blockIdx.z * ZSPAN;
    const bool lastz = (blockIdx.z == NZ - 1);
    const int pix = (h0p + ty) * WOUT + (w0p + tx);
    const unsigned short* xus = (const unsigned short*)xin;

    __shared__ __align__(16) unsigned su[2 * SUWORDS];

    uint4 dat[6];
    stageA2(xus, tid, h0p, w0p, zb, dat);

    float asum = 0.f;
    unsigned gp[38];
#pragma unroll
    for (int p = 0; p < 38; ++p) {
        int c0 = 2 * p, c1 = 2 * p + 1;
        float w0 = lg1[c0 * NPIX + pix];
        float w1 = (c1 < 75) ? lg1[c1 * NPIX + pix] : 0.f;
        unsigned b0 = bf16bits(w0), b1 = bf16bits(w1);
        asum += fabsf(__uint_as_float(b0 << 16)) +
                fabsf(__uint_as_float(b1 << 16));
        gp[p] = b0 | (b1 << 16);
    }
    const float inv = 1.f / fmaxf(asum, 1e-12f);

    const int pbase = (ty * ROWSTRIDE + tx + 6) * PIXW;

    float l = 0.f, s_acc = 0.f;

    scat2((unsigned short*)su, tid, dat); // first chunk -> buf0
    int pb = 0;
    for (int d0 = zb; d0 < zb + ZSPAN; d0 += CHUNK) { // 6 full chunks
        __syncthreads();
        const bool hn = lastz ? (d0 + CHUNK < DOUT)
                              : (d0 + CHUNK < zb + ZSPAN);
        if (hn) stageA2(xus, tid, h0p, w0p, d0 + CHUNK, dat);

        const unsigned* sw = su + pb * SUWORDS + pbase;
        float acc[16];
#pragma unroll
        for (int d = 0; d < 16; ++d) acc[d] = 0.f;
        __builtin_amdgcn_s_setprio(1);
#pragma unroll
        for (int i = 0; i < 5; ++i) {
#pragma unroll
            for (int j = 0; j < 5; ++j) {
                const int t = i * 5 + j;
                TAP16(sw + (i * ROWSTRIDE + j) * PIXW, t);
            }
        }
        __builtin_amdgcn_s_setprio(0);

        if (hn) scat2((unsigned short*)(su + (pb ^ 1) * SUWORDS), tid, dat);

        {
            float sum = 0.f, ssum = 0.f;
#pragma unroll
            for (int d = 0; d < 16; ++d) {
                float e = __expf(-acc[d] * inv);
                sum += e;
                ssum += e * (float)(d0 + d);
            }
            l += sum;
            s_acc += ssum;
        }
        pb ^= 1;
    }

    if (lastz) { // epilogue: d = 192 only
        __syncthreads();
        const unsigned* sw = su + pb * SUWORDS + pbase;
        float acc0 = 0.f;
#pragma unroll
        for (int i = 0; i < 5; ++i) {
#pragma unroll
            for (int j = 0; j < 5; ++j) {
                const int t = i * 5 + j;
                TAPTAIL(sw + (i * ROWSTRIDE + j) * PIXW, t);
            }
        }
        float e = __expf(-acc0 * inv);
        l += e;
        s_acc += e * 192.f;
    }

    float* pz = part + (size_t)blockIdx.z * 2 * NPIX;
    pz[pix] = l;
    pz[NPIX + pix] = s_acc;
}

// ---------------------------------------------------------------------------
// Kernel 4: merge NZ (l, s) partials per pixel -> disparity (plain adds —
// no max/rescale needed since partials share the exp reference).
// ---------------------------------------------------------------------------
__global__ void reduce2_kernel(const float* __restrict__ part,
                               float* __restrict__ out) {
    int pix = blockIdx.x * blockDim.x + threadIdx.x;
    float L = part[pix] + part[2 * NPIX + pix];
    float S = part[NPIX + pix] + part[3 * NPIX + pix];
    out[pix] = S / L;
}

// ---------------------------------------------------------------------------
extern "C" void kernel_launch(void* const* d_in, const int* in_sizes, int n_in,
                              void* d_out, int out_size, void* d_ws,
                              size_t ws_size, hipStream_t stream) {
    const float* x = (const float*)d_in[0];
    const float* lg1 = (const float*)d_in[1];
    const float* cw = (const float*)d_in[2];
    float* out = (float*)d_out;

    // ws: c fp32 [100352] | region A bf16 [NUPS] | region B bf16 [NUPS].
    // conv partials [8][NCONV] overlay region B; lga1 writes y1 to region B;
    // lga2 writes (l,s) partials to region A.
    float* c = (float*)d_ws;
    __hip_bfloat16* regA = (__hip_bfloat16*)((char*)d_ws + (size_t)NCONV * 4);
    __hip_bfloat16* y1 = regA + (size_t)NUPS;
    float* cpart = (float*)y1;
    float* part = (float*)regA;

    dim3 cgrid(NCONV / 1024, CGRP); // 98 x 8; each thread does 4 w-outputs
    conv3d_kernel<<<cgrid, 256, 0, stream>>>(x, cw, cpart);
    convfold_kernel<<<NCONV / 1024, 256, 0, stream>>>(cpart, c);

    dim3 grid(WOUT / 16, HOUT / 16, NZ); // 32 x 16 x 2 = 1024 blocks
    lga1_kernel<<<grid, 256, 0, stream>>>(c, lg1, y1);
    lga2_kernel<<<grid, 256, 0, stream>>>(y1, lg1, part);

    reduce2_kernel<<<NPIX / 256, 256, 0, stream>>>(part, out);
}

// Round 18
// 280.708 us; speedup vs baseline: 1.0625x; 1.0625x over previous
//
#include <hip/hip_runtime.h>
#include <hip/hip_bf16.h>

#define DIN 49
#define HIN 32
#define WIN 64
#define CIN 32
#define DOUT 193
#define HOUT 256
#define WOUT 512
#define NPIX (HOUT * WOUT)      // 131072
#define NUPS (DOUT * NPIX)      // 25296896
#define NCONV (DIN * HIN * WIN) // 100352
#define NZ 1 // R17 measured: 3rd block/CU never materializes -> NZ=2 reverted
#define CGRP 8 // conv channel groups (4 ci each)

// LGA LDS geometry: bf16-packed, d-contiguous per pixel, dot2-consumed
// (R13). CHUNK=16 (R14): PIXW=10 words/pixel, double-buffered 2 x 25.8 KB.
// 12 full chunks + 1-plane epilogue (d=192) — R16 measured best.
#define ROWSTRIDE 33 // pixel-row stride in pixels
#define PIXW 10      // words per pixel
#define SUWORDS (20 * ROWSTRIDE * PIXW) // 6600 words per buffer
#define CHUNK 16
#define NPL 18   // CHUNK + 2 halo planes
// staging jobs: 20 rows x 4 segs x 18 planes = 1440; k<6 with tail 160
#define JGUARD(k, tid) ((k) < 5 || (tid) < 160)

typedef __attribute__((ext_vector_type(2))) float v2f;

// v_dot2_f32_bf16: d = a.lo*b.lo + a.hi*b.hi + c (packed bf16 operands).
__device__ __forceinline__ float dot2bf(unsigned a, unsigned b, float c) {
    float d;
    asm("v_dot2_f32_bf16 %0, %1, %2, %3"
        : "=v"(d)
        : "v"(a), "v"(b), "v"(c));
    return d;
}

// ---------------------------------------------------------------------------
// Kernel 1: 3x3x3 conv, 32 -> 1 ch, zero pad 1, split 8 ways over channels.
// 4-wide w-vectorized (R10 measured win).
// ---------------------------------------------------------------------------
__global__ void conv3d_kernel(const float* __restrict__ x,
                              const float* __restrict__ w,
                              float* __restrict__ partial) {
    __shared__ float ws[4 * 27];
    const int grp = blockIdx.y;
    for (int t = threadIdx.x; t < 4 * 27; t += blockDim.x)
        ws[t] = w[grp * (4 * 27) + t];
    __syncthreads();

    int idx4 = blockIdx.x * blockDim.x + threadIdx.x; // 25088 = 98*256 exact
    int w4 = idx4 & 15;  // WIN/4 = 16
    int t2 = idx4 >> 4;
    int hq = t2 & 31;    // HIN = 32
    int dq = t2 >> 5;    // dq in [0, 49)
    int wq0 = w4 * 4;

    float acc0 = 0.f, acc1 = 0.f, acc2 = 0.f, acc3 = 0.f;
    const float* xg = x + (size_t)grp * 4 * NCONV;
#pragma unroll
    for (int cl = 0; cl < 4; ++cl) {
        const float* xb = xg + cl * NCONV;
        const float* wb = ws + cl * 27;
#pragma unroll
        for (int kd = 0; kd < 3; ++kd) {
            int zd = dq + kd - 1;
            if (zd < 0 || zd >= DIN) continue;
#pragma unroll
            for (int kh = 0; kh < 3; ++kh) {
                int zh = hq + kh - 1;
                if (zh < 0 || zh >= HIN) continue;
                const float* row = xb + (zd * HIN + zh) * WIN;
                float4 v = *(const float4*)(row + wq0);
                float xl = (wq0 > 0) ? row[wq0 - 1] : 0.f;
                float xr = (wq0 < WIN - 4) ? row[wq0 + 4] : 0.f;
                float w0 = wb[(kd * 3 + kh) * 3 + 0];
                float w1 = wb[(kd * 3 + kh) * 3 + 1];
                float w2 = wb[(kd * 3 + kh) * 3 + 2];
                acc0 = fmaf(w0, xl, acc0);
                acc0 = fmaf(w1, v.x, acc0);
                acc0 = fmaf(w2, v.y, acc0);
                acc1 = fmaf(w0, v.x, acc1);
                acc1 = fmaf(w1, v.y, acc1);
                acc1 = fmaf(w2, v.z, acc1);
                acc2 = fmaf(w0, v.y, acc2);
                acc2 = fmaf(w1, v.z, acc2);
                acc2 = fmaf(w2, v.w, acc2);
                acc3 = fmaf(w0, v.z, acc3);
                acc3 = fmaf(w1, v.w, acc3);
                acc3 = fmaf(w2, xr, acc3);
            }
        }
    }
    float4 o4 = make_float4(acc0, acc1, acc2, acc3);
    *(float4*)(partial + (size_t)grp * NCONV + (size_t)idx4 * 4) = o4;
}

// ---------------------------------------------------------------------------
// Kernel 1b: fold 8 conv partials -> c. float4-vectorized.
// ---------------------------------------------------------------------------
__global__ void convfold_kernel(const float* __restrict__ partial,
                                float* __restrict__ c) {
    int i4 = blockIdx.x * blockDim.x + threadIdx.x; // NCONV/4 = 25088
    float4 s = *(const float4*)(partial + (size_t)i4 * 4);
#pragma unroll
    for (int g = 1; g < CGRP; ++g) {
        float4 v = *(const float4*)(partial + (size_t)g * NCONV +
                                    (size_t)i4 * 4);
        s.x += v.x;
        s.y += v.y;
        s.z += v.z;
        s.w += v.w;
    }
    *(float4*)(c + (size_t)i4 * 4) = s;
}

__device__ __forceinline__ unsigned short bf16bits(float f) {
    __hip_bfloat16 h = __float2bfloat16(f);
    unsigned short b;
    __builtin_memcpy(&b, &h, 2);
    return b;
}

// Tap body for CHUNK=16: 9 LDS words (4x b64 + b32), 32 dot2, one set of
// packed weight words per tap (amortized over 16 outputs). gp[] holds bf16
// channel pairs; parity of t selects halves at compile time.
#define TAP16(sp, t)                                                 \
    do {                                                             \
        unsigned u0, u1, u2, u3, u4, u5, u6, u7, u8;                 \
        { uint2 q = *(const uint2*)(sp);       u0 = q.x; u1 = q.y; } \
        { uint2 q = *(const uint2*)((sp) + 2); u2 = q.x; u3 = q.y; } \
        { uint2 q = *(const uint2*)((sp) + 4); u4 = q.x; u5 = q.y; } \
        { uint2 q = *(const uint2*)((sp) + 6); u6 = q.x; u7 = q.y; } \
        u8 = (sp)[8];                                                \
        const unsigned g0w = gp[(t) >> 1];                           \
        const unsigned g1w = gp[(25 + (t)) >> 1];                    \
        const unsigned g2w = gp[(50 + (t)) >> 1];                    \
        unsigned W10, W2z, Wz1, W02;                                 \
        if ((t) & 1) {                                               \
            W10 = (g1w & 0xFFFFu) | (g0w & 0xFFFF0000u);             \
            W2z = g2w >> 16;                                         \
            Wz1 = g1w << 16;                                         \
            W02 = (g0w >> 16) | (g2w & 0xFFFF0000u);                 \
        } else {                                                     \
            W10 = (g1w >> 16) | (g0w << 16);                         \
            W2z = g2w & 0xFFFFu;                                     \
            Wz1 = g1w & 0xFFFF0000u;                                 \
            W02 = (g0w & 0xFFFFu) | (g2w << 16);                     \
        }                                                            \
        acc[0] = dot2bf(u0, W10, acc[0]);                            \
        acc[0] = dot2bf(u1, W2z, acc[0]);                            \
        acc[1] = dot2bf(u0, Wz1, acc[1]);                            \
        acc[1] = dot2bf(u1, W02, acc[1]);                            \
        acc[2] = dot2bf(u1, W10, acc[2]);                            \
        acc[2] = dot2bf(u2, W2z, acc[2]);                            \
        acc[3] = dot2bf(u1, Wz1, acc[3]);                            \
        acc[3] = dot2bf(u2, W02, acc[3]);                            \
        acc[4] = dot2bf(u2, W10, acc[4]);                            \
        acc[4] = dot2bf(u3, W2z, acc[4]);                            \
        acc[5] = dot2bf(u2, Wz1, acc[5]);                            \
        acc[5] = dot2bf(u3, W02, acc[5]);                            \
        acc[6] = dot2bf(u3, W10, acc[6]);                            \
        acc[6] = dot2bf(u4, W2z, acc[6]);                            \
        acc[7] = dot2bf(u3, Wz1, acc[7]);                            \
        acc[7] = dot2bf(u4, W02, acc[7]);                            \
        acc[8] = dot2bf(u4, W10, acc[8]);                            \
        acc[8] = dot2bf(u5, W2z, acc[8]);                            \
        acc[9] = dot2bf(u4, Wz1, acc[9]);                            \
        acc[9] = dot2bf(u5, W02, acc[9]);                            \
        acc[10] = dot2bf(u5, W10, acc[10]);                          \
        acc[10] = dot2bf(u6, W2z, acc[10]);                          \
        acc[11] = dot2bf(u5, Wz1, acc[11]);                          \
        acc[11] = dot2bf(u6, W02, acc[11]);                          \
        acc[12] = dot2bf(u6, W10, acc[12]);                          \
        acc[12] = dot2bf(u7, W2z, acc[12]);                          \
        acc[13] = dot2bf(u6, Wz1, acc[13]);                          \
        acc[13] = dot2bf(u7, W02, acc[13]);                          \
        acc[14] = dot2bf(u7, W10, acc[14]);                          \
        acc[14] = dot2bf(u8, W2z, acc[14]);                          \
        acc[15] = dot2bf(u7, Wz1, acc[15]);                          \
        acc[15] = dot2bf(u8, W02, acc[15]);                          \
    } while (0)

// Tail tap (d = 192 only): out = g1*u[191] + g0*u[192] (+ g2*0 — u[193]
// is zero-padded). One dot2 per tap on word 0.
#define TAPTAIL(sp, t)                                               \
    do {                                                             \
        unsigned u0 = (sp)[0];                                       \
        const unsigned g0w = gp[(t) >> 1];                           \
        const unsigned g1w = gp[(25 + (t)) >> 1];                    \
        unsigned W10;                                                \
        if ((t) & 1)                                                 \
            W10 = (g1w & 0xFFFFu) | (g0w & 0xFFFF0000u);             \
        else                                                         \
            W10 = (g1w >> 16) | (g0w << 16);                         \
        acc0 = dot2bf(u0, W10, acc0);                                \
    } while (0)

// job decode (1440 jobs): seg in [0,4), dl in [0,18), r in [0,20)
__device__ __forceinline__ void jdec(int j, int& seg, int& dl, int& r) {
    seg = j & 3;
    int rowjob = j >> 2; // [0, 360)
    dl = rowjob / 20;
    r = rowjob - dl * 20;
}

// ---------------------------------------------------------------------------
// lga1 staging phase A: trilinear d/h-lerp from c (L2-hot) into packed
// bf16 regs (9 regs for 6 jobs). Issued EARLY (T14).
// ---------------------------------------------------------------------------
__device__ __forceinline__ void stageA1(const float* __restrict__ cvol,
                                        int tid, int h0p, int w0p, int dstart,
                                        unsigned (&aq0)[6], unsigned (&aq2)[3]) {
    aq2[0] = 0u;
    aq2[1] = 0u;
    aq2[2] = 0u;
#pragma unroll
    for (int k = 0; k < 6; ++k) {
        const bool a = JGUARD(k, tid);
        int j = tid + k * 256;
        int seg, dl, r;
        jdec(j, seg, dl, r);
        int gh = h0p - 2 + r;
        int gwb = w0p - 8 + seg * 8;
        int gd = dstart - 1 + dl;
        if (a && gd >= 0 && gd < DOUT && gh >= 0 && gh < HOUT && gwb >= 0 &&
            (gwb + 8) <= WOUT) {
            float fd = (gd + 0.5f) * (49.0f / 193.0f) - 0.5f;
            fd = fminf(fmaxf(fd, 0.f), (float)(DIN - 1));
            int d0c = min((int)fd, DIN - 2);
            float ad = fd - (float)d0c;
            float fh = (gh + 0.5f) * 0.125f - 0.5f;
            fh = fminf(fmaxf(fh, 0.f), (float)(HIN - 1));
            int h0c = min((int)fh, HIN - 2);
            float ah = fh - (float)h0c;
            int g = gwb >> 3;
            int cm1 = max(g - 1, 0);
            int cp1 = min(g + 1, WIN - 1);
            const float* p00 = cvol + (d0c * HIN + h0c) * WIN;
            const float* p01 = p00 + WIN;
            const float* p10 = p00 + HIN * WIN;
            const float* p11 = p10 + WIN;
            float q00, q01, q10, q11, a0, a1, a2;
            q00 = p00[cm1]; q01 = p01[cm1];
            q10 = p10[cm1]; q11 = p11[cm1];
            a0 = (q00 + ah * (q01 - q00)) * (1.f - ad) +
                 (q10 + ah * (q11 - q10)) * ad;
            q00 = p00[g]; q01 = p01[g];
            q10 = p10[g]; q11 = p11[g];
            a1 = (q00 + ah * (q01 - q00)) * (1.f - ad) +
                 (q10 + ah * (q11 - q10)) * ad;
            q00 = p00[cp1]; q01 = p01[cp1];
            q10 = p10[cp1]; q11 = p11[cp1];
            a2 = (q00 + ah * (q01 - q00)) * (1.f - ad) +
                 (q10 + ah * (q11 - q10)) * ad;
            aq0[k] = (unsigned)bf16bits(a0) | ((unsigned)bf16bits(a1) << 16);
            aq2[k >> 1] |= ((unsigned)bf16bits(a2)) << ((k & 1) * 16);
        } else {
            aq0[k] = 0u;
        }
    }
}

// lga1 scatter phase B: w-lerp from regs, bf16 half-word stores into LDS.
__device__ __forceinline__ void scat1(unsigned short* __restrict__ su16,
                                      int tid, const unsigned (&aq0)[6],
                                      const unsigned (&aq2)[3]) {
#pragma unroll
    for (int k = 0; k < 6; ++k) {
        if (JGUARD(k, tid)) {
            int j = tid + k * 256;
            int seg, dl, r;
            jdec(j, seg, dl, r);
            int hb = (r * ROWSTRIDE + seg * 8) * (2 * PIXW) + dl;
            float a0 = __uint_as_float(aq0[k] << 16);
            float a1 = __uint_as_float(aq0[k] & 0xFFFF0000u);
            float a2 = __uint_as_float((k & 1) ? (aq2[k >> 1] & 0xFFFF0000u)
                                               : (aq2[k >> 1] << 16));
            float d01 = a1 - a0, d12 = a2 - a1;
            su16[hb + 0 * 2 * PIXW] = bf16bits(a0 + 0.5625f * d01);
            su16[hb + 1 * 2 * PIXW] = bf16bits(a0 + 0.6875f * d01);
            su16[hb + 2 * 2 * PIXW] = bf16bits(a0 + 0.8125f * d01);
            su16[hb + 3 * 2 * PIXW] = bf16bits(a0 + 0.9375f * d01);
            su16[hb + 4 * 2 * PIXW] = bf16bits(a1 + 0.0625f * d12);
            su16[hb + 5 * 2 * PIXW] = bf16bits(a1 + 0.1875f * d12);
            su16[hb + 6 * 2 * PIXW] = bf16bits(a1 + 0.3125f * d12);
            su16[hb + 7 * 2 * PIXW] = bf16bits(a1 + 0.4375f * d12);
        }
    }
}

// lga2 staging phase A: one uint4 (8 bf16) HBM load per job into regs.
__device__ __forceinline__ void stageA2(const unsigned short* __restrict__ xus,
                                        int tid, int h0p, int w0p, int dstart,
                                        uint4 (&dat)[6]) {
#pragma unroll
    for (int k = 0; k < 6; ++k) {
        const bool a = JGUARD(k, tid);
        int j = tid + k * 256;
        int seg, dl, r;
        jdec(j, seg, dl, r);
        int gh = h0p - 2 + r;
        int gwb = w0p - 8 + seg * 8;
        int gd = dstart - 1 + dl;
        uint4 v = make_uint4(0u, 0u, 0u, 0u);
        if (a && gd >= 0 && gd < DOUT && gh >= 0 && gh < HOUT && gwb >= 0 &&
            (gwb + 8) <= WOUT)
            v = *(const uint4*)(xus + (size_t)gd * NPIX + gh * WOUT + gwb);
        dat[k] = v;
    }
}

// lga2 scatter phase B: bf16 half-word stores straight from packed regs.
__device__ __forceinline__ void scat2(unsigned short* __restrict__ su16,
                                      int tid, const uint4 (&dat)[6]) {
#pragma unroll
    for (int k = 0; k < 6; ++k) {
        if (JGUARD(k, tid)) {
            int j = tid + k * 256;
            int seg, dl, r;
            jdec(j, seg, dl, r);
            int hb = (r * ROWSTRIDE + seg * 8) * (2 * PIXW) + dl;
            su16[hb + 0 * 2 * PIXW] = (unsigned short)(dat[k].x);
            su16[hb + 1 * 2 * PIXW] = (unsigned short)(dat[k].x >> 16);
            su16[hb + 2 * 2 * PIXW] = (unsigned short)(dat[k].y);
            su16[hb + 3 * 2 * PIXW] = (unsigned short)(dat[k].y >> 16);
            su16[hb + 4 * 2 * PIXW] = (unsigned short)(dat[k].z);
            su16[hb + 5 * 2 * PIXW] = (unsigned short)(dat[k].z >> 16);
            su16[hb + 6 * 2 * PIXW] = (unsigned short)(dat[k].w);
            su16[hb + 7 * 2 * PIXW] = (unsigned short)(dat[k].w >> 16);
        }
    }
}

// ---------------------------------------------------------------------------
// LGA pass 1. bf16 double-buffered su + dot2 taps; 12 full chunks + light
// 1-plane epilogue. s_setprio(1) around the tap loop (T5, R15 measured win).
// amdgpu_num_vgpr(128) pin. Byte-identical to R16 (282.3 us best).
// ---------------------------------------------------------------------------
__global__ __launch_bounds__(256)
__attribute__((amdgpu_num_vgpr(128))) void lga1_kernel(
    const float* __restrict__ cvol,
    const float* __restrict__ lg1,
    __hip_bfloat16* __restrict__ yout) {
    const int tid = threadIdx.x;
    const int tx = tid & 15;
    const int ty = tid >> 4;
    const int w0p = blockIdx.x * 16;
    const int h0p = blockIdx.y * 16;
    const int pix = (h0p + ty) * WOUT + (w0p + tx);

    __shared__ __align__(16) unsigned su[2 * SUWORDS];

    // prologue phase A (chunk 0): loads land under the guidance preamble
    unsigned aq0[6], aq2[3];
    stageA1(cvol, tid, h0p, w0p, 0, aq0, aq2);

    // ---- guidance: single pass, un-normalized, bf16 pairs (38 regs) ----
    float asum = 0.f;
    unsigned gp[38];
#pragma unroll
    for (int p = 0; p < 38; ++p) {
        int c0 = 2 * p, c1 = 2 * p + 1;
        float w0 = lg1[c0 * NPIX + pix];
        float w1 = (c1 < 75) ? lg1[c1 * NPIX + pix] : 0.f;
        unsigned b0 = bf16bits(w0), b1 = bf16bits(w1);
        asum += fabsf(__uint_as_float(b0 << 16)) +
                fabsf(__uint_as_float(b1 << 16));
        gp[p] = b0 | (b1 << 16);
    }
    const float inv = 1.f / fmaxf(asum, 1e-12f);

    const int pbase = (ty * ROWSTRIDE + tx + 6) * PIXW;
    __hip_bfloat16* ybase = yout + pix;

    scat1((unsigned short*)su, tid, aq0, aq2); // chunk 0 -> buf0
    int pb = 0;
    for (int d0 = 0; d0 + CHUNK < DOUT; d0 += CHUNK) { // 12 full chunks
        __syncthreads(); // buf[pb] writes visible; buf[pb^1] readers done
        stageA1(cvol, tid, h0p, w0p, d0 + CHUNK, aq0, aq2);

        const unsigned* sw = su + pb * SUWORDS + pbase;
        float acc[16];
#pragma unroll
        for (int d = 0; d < 16; ++d) acc[d] = 0.f;
        __builtin_amdgcn_s_setprio(1);
#pragma unroll
        for (int i = 0; i < 5; ++i) {
#pragma unroll
            for (int j = 0; j < 5; ++j) {
                const int t = i * 5 + j;
                TAP16(sw + (i * ROWSTRIDE + j) * PIXW, t);
            }
        }
        __builtin_amdgcn_s_setprio(0);

        scat1((unsigned short*)(su + (pb ^ 1) * SUWORDS), tid, aq0, aq2);

#pragma unroll
        for (int dd = 0; dd < CHUNK; ++dd)
            ybase[(size_t)(d0 + dd) * NPIX] = __float2bfloat16(acc[dd] * inv);
        pb ^= 1;
    }

    // epilogue: d = 192 only — one dot2 per tap
    __syncthreads();
    {
        const unsigned* sw = su + pb * SUWORDS + pbase;
        float acc0 = 0.f;
#pragma unroll
        for (int i = 0; i < 5; ++i) {
#pragma unroll
            for (int j = 0; j < 5; ++j) {
                const int t = i * 5 + j;
                TAPTAIL(sw + (i * ROWSTRIDE + j) * PIXW, t);
            }
        }
        ybase[(size_t)192 * NPIX] = __float2bfloat16(acc0 * inv);
    }
}

// ---------------------------------------------------------------------------
// LGA pass 2: R16 structure + no-max softmin (verified correct in R17:
// |v| <= max|u| = O(10) since guidance is L1-normalized -> raw expf safe,
// all-positive sums). Drops the 16-wide fmax tree + rescale per chunk.
// ---------------------------------------------------------------------------
__global__ __launch_bounds__(256)
__attribute__((amdgpu_num_vgpr(128))) void lga2_kernel(
    const __hip_bfloat16* __restrict__ xin,
    const float* __restrict__ lg1,
    float* __restrict__ out) {
    const int tid = threadIdx.x;
    const int tx = tid & 15;
    const int ty = tid >> 4;
    const int w0p = blockIdx.x * 16;
    const int h0p = blockIdx.y * 16;
    const int pix = (h0p + ty) * WOUT + (w0p + tx);
    const unsigned short* xus = (const unsigned short*)xin;

    __shared__ __align__(16) unsigned su[2 * SUWORDS];

    uint4 dat[6];
    stageA2(xus, tid, h0p, w0p, 0, dat);

    float asum = 0.f;
    unsigned gp[38];
#pragma unroll
    for (int p = 0; p < 38; ++p) {
        int c0 = 2 * p, c1 = 2 * p + 1;
        float w0 = lg1[c0 * NPIX + pix];
        float w1 = (c1 < 75) ? lg1[c1 * NPIX + pix] : 0.f;
        unsigned b0 = bf16bits(w0), b1 = bf16bits(w1);
        asum += fabsf(__uint_as_float(b0 << 16)) +
                fabsf(__uint_as_float(b1 << 16));
        gp[p] = b0 | (b1 << 16);
    }
    const float inv = 1.f / fmaxf(asum, 1e-12f);

    const int pbase = (ty * ROWSTRIDE + tx + 6) * PIXW;

    float l = 0.f, s_acc = 0.f;

    scat2((unsigned short*)su, tid, dat); // chunk 0 -> buf0
    int pb = 0;
    for (int d0 = 0; d0 + CHUNK < DOUT; d0 += CHUNK) { // 12 full chunks
        __syncthreads();
        stageA2(xus, tid, h0p, w0p, d0 + CHUNK, dat);

        const unsigned* sw = su + pb * SUWORDS + pbase;
        float acc[16];
#pragma unroll
        for (int d = 0; d < 16; ++d) acc[d] = 0.f;
        __builtin_amdgcn_s_setprio(1);
#pragma unroll
        for (int i = 0; i < 5; ++i) {
#pragma unroll
            for (int j = 0; j < 5; ++j) {
                const int t = i * 5 + j;
                TAP16(sw + (i * ROWSTRIDE + j) * PIXW, t);
            }
        }
        __builtin_amdgcn_s_setprio(0);

        scat2((unsigned short*)(su + (pb ^ 1) * SUWORDS), tid, dat);

        {
            float sum = 0.f, ssum = 0.f;
#pragma unroll
            for (int d = 0; d < 16; ++d) {
                float e = __expf(-acc[d] * inv);
                sum += e;
                ssum += e * (float)(d0 + d);
            }
            l += sum;
            s_acc += ssum;
        }
        pb ^= 1;
    }

    // epilogue: d = 192 only
    __syncthreads();
    {
        const unsigned* sw = su + pb * SUWORDS + pbase;
        float acc0 = 0.f;
#pragma unroll
        for (int i = 0; i < 5; ++i) {
#pragma unroll
            for (int j = 0; j < 5; ++j) {
                const int t = i * 5 + j;
                TAPTAIL(sw + (i * ROWSTRIDE + j) * PIXW, t);
            }
        }
        float e = __expf(-acc0 * inv);
        l += e;
        s_acc += e * 192.f;
    }

    out[pix] = s_acc / l;
}

// ---------------------------------------------------------------------------
extern "C" void kernel_launch(void* const* d_in, const int* in_sizes, int n_in,
                              void* d_out, int out_size, void* d_ws,
                              size_t ws_size, hipStream_t stream) {
    const float* x = (const float*)d_in[0];
    const float* lg1 = (const float*)d_in[1];
    const float* cw = (const float*)d_in[2];
    float* out = (float*)d_out;

    // ws: c fp32 [100352] | region A bf16 [NUPS] | region B bf16 [NUPS].
    // conv partials [8][NCONV] overlay region B; lga1 writes y1 to region B.
    float* c = (float*)d_ws;
    __hip_bfloat16* regA = (__hip_bfloat16*)((char*)d_ws + (size_t)NCONV * 4);
    __hip_bfloat16* y1 = regA + (size_t)NUPS;
    float* cpart = (float*)y1;

    dim3 cgrid(NCONV / 1024, CGRP); // 98 x 8; each thread does 4 w-outputs
    conv3d_kernel<<<cgrid, 256, 0, stream>>>(x, cw, cpart);
    convfold_kernel<<<NCONV / 1024, 256, 0, stream>>>(cpart, c);

    dim3 grid(WOUT / 16, HOUT / 16, NZ); // 32 x 16 x 1 = 512 blocks
    lga1_kernel<<<grid, 256, 0, stream>>>(c, lg1, y1);
    lga2_kernel<<<grid, 256, 0, stream>>>(y1, lg1, out);
}